// Round 1
// baseline (125.662 us; speedup 1.0000x reference)
//
#include <hip/hip_runtime.h>

// Problem constants (from setup_inputs): B=4, S=2048, D=1024, G=256, I=1024, H=16
#define BB 4
#define SS 2048
#define DD 1024
#define II 1024

// ---------------------------------------------------------------------------
// Algebraic collapse of the reference:
//   keys are identical across the sequence -> scores constant per row ->
//   softmax uniform (1/S) -> attended = mean_s(x @ Wv), broadcast over s ->
//   out[b,s,:] = ((mean_s x[b,s,:]) @ Wv) @ Wo   (Wq/Wk/structure unused)
// ---------------------------------------------------------------------------

// K1: xbar[b,d] = (1/S) * sum_s x[b,s,d]
// grid (S/CHUNK, B), block 256; each thread owns 4 consecutive d (float4).
constexpr int CHUNK = 64;

__global__ void k_mean(const float* __restrict__ x, float* __restrict__ xbar) {
    const int b  = blockIdx.y;
    const int s0 = blockIdx.x * CHUNK;
    const int d4 = threadIdx.x;                    // 0..255 -> d = d4*4 .. +3
    const float4* xr = (const float4*)(x + (size_t)b * SS * DD);
    float4 acc = make_float4(0.f, 0.f, 0.f, 0.f);
    #pragma unroll 4
    for (int r = 0; r < CHUNK; ++r) {
        float4 v = xr[(size_t)(s0 + r) * (DD / 4) + d4];
        acc.x += v.x; acc.y += v.y; acc.z += v.z; acc.w += v.w;
    }
    const float inv = 1.0f / (float)SS;
    float* dst = xbar + b * DD + d4 * 4;
    atomicAdd(dst + 0, acc.x * inv);
    atomicAdd(dst + 1, acc.y * inv);
    atomicAdd(dst + 2, acc.z * inv);
    atomicAdd(dst + 3, acc.w * inv);
}

// K2/K3: vout[b,i] += sum_d vin[b,d] * W[d,i]   (W row-major [K,N])
// grid (N/256, K/DCH), block 256. Split-K with atomics; vin chunk staged in LDS.
constexpr int DCH = 128;

__global__ void k_gemv(const float* __restrict__ vin, const float* __restrict__ W,
                       float* __restrict__ vout, int K, int N) {
    const int i  = blockIdx.x * 256 + threadIdx.x;
    const int d0 = blockIdx.y * DCH;
    __shared__ float xs[BB][DCH];
    for (int idx = threadIdx.x; idx < BB * DCH; idx += 256) {
        int b = idx / DCH, d = idx % DCH;
        xs[b][d] = vin[b * K + d0 + d];
    }
    __syncthreads();
    float a0 = 0.f, a1 = 0.f, a2 = 0.f, a3 = 0.f;
    #pragma unroll 8
    for (int d = 0; d < DCH; ++d) {
        float w = W[(size_t)(d0 + d) * N + i];
        a0 += xs[0][d] * w;
        a1 += xs[1][d] * w;
        a2 += xs[2][d] * w;
        a3 += xs[3][d] * w;
    }
    atomicAdd(&vout[0 * N + i], a0);
    atomicAdd(&vout[1 * N + i], a1);
    atomicAdd(&vout[2 * N + i], a2);
    atomicAdd(&vout[3 * N + i], a3);
}

// K4: out[b,s,:] = row[b,:]  (float4 broadcast write)
__global__ void k_bcast(const float* __restrict__ row, float4* __restrict__ out) {
    const size_t g = (size_t)blockIdx.x * blockDim.x + threadIdx.x;  // over B*S*D/4
    const int per_b = SS * (DD / 4);
    const int b  = (int)(g / per_b);
    const int d4 = (int)(g % (DD / 4));
    const float4* r = (const float4*)row;
    out[g] = r[b * (DD / 4) + d4];
}

extern "C" void kernel_launch(void* const* d_in, const int* in_sizes, int n_in,
                              void* d_out, int out_size, void* d_ws, size_t ws_size,
                              hipStream_t stream) {
    const float* x  = (const float*)d_in[0];  // inputs_embeds [B,S,D]
    const float* Wv = (const float*)d_in[4];  // [D,I]
    const float* Wo = (const float*)d_in[5];  // [I,D]
    float* out = (float*)d_out;

    float* xbar = (float*)d_ws;        // [B,D]
    float* tbuf = xbar + BB * DD;      // [B,I]
    float* orow = tbuf + BB * II;      // [B,D]

    // ws is re-poisoned to 0xAA before every timed launch -> zero what we use.
    hipMemsetAsync(d_ws, 0, (size_t)(BB * DD + BB * II + BB * DD) * sizeof(float), stream);

    k_mean<<<dim3(SS / CHUNK, BB), 256, 0, stream>>>(x, xbar);
    k_gemv<<<dim3(II / 256, DD / DCH), 256, 0, stream>>>(xbar, Wv, tbuf, DD, II);
    k_gemv<<<dim3(DD / 256, II / DCH), 256, 0, stream>>>(tbuf, Wo, orow, II, DD);

    const size_t total4 = (size_t)BB * SS * DD / 4;
    k_bcast<<<(int)(total4 / 256), 256, 0, stream>>>(orow, (float4*)out);
}